// Round 7
// baseline (1644.999 us; speedup 1.0000x reference)
//
#include <hip/hip_runtime.h>

#define TSTEPS 2048
#define NBATCH 512
#define H1 64
#define H2 16
#define RING 32

typedef float v2f __attribute__((ext_vector_type(2)));
typedef float v4f __attribute__((ext_vector_type(4)));

__device__ __forceinline__ float fsig(float x) {
    return __builtin_amdgcn_rcpf(1.0f + __builtin_amdgcn_exp2f(-1.4426950408889634f * x));
}
__device__ __forceinline__ float ftanh(float x) {
    // tanh(x) = 1 - 2/(exp2(2x*log2e)+1); saturates correctly at +-inf
    return 1.0f - 2.0f * __builtin_amdgcn_rcpf(1.0f + __builtin_amdgcn_exp2f(2.8853900817779268f * x));
}
// branchless per-lane activation: k2==1 -> sigmoid(x); k2==2 -> tanh(x)=2*sig(2x)-1
__device__ __forceinline__ float act(float x, float k2) {
    return k2 * fsig(k2 * x) - (k2 - 1.0f);
}

template<int CTRL>
__device__ __forceinline__ float dpp_add(float v) {
    int m = __builtin_amdgcn_mov_dpp(__float_as_int(v), CTRL, 0xF, 0xF, true);
    return v + __int_as_float(m);
}
__device__ __forceinline__ float reduce2(float s) {   // all-reduce over lane pairs
    return dpp_add<0xB1>(s);                          // quad_perm xor1
}
__device__ __forceinline__ float reduce8(float s) {   // all-reduce over 8-lane groups
    s = dpp_add<0xB1>(s);    // xor1
    s = dpp_add<0x4E>(s);    // xor2
    s = dpp_add<0x141>(s);   // 8-lane half mirror (uniform quads -> completes 8-sum)
    return s;
}

// 512 threads: one (channel,gate) row per lane -> minimal per-lane weight set.
// L1: lane = j*8 + g*2 + s2   (64 ch x 4 gates x 2 k-halves), 16 v2f weights
// L2: lane = m*32 + g2*8 + s8 (16 ch x 4 gates x 8 k-slices), 5 v2f weights
// Demand ~95 VGPR < 128 budget (amdgpu_waves_per_eu(4,4) pins 4 waves/SIMD,
// which the 512-block grid provides anyway) -> no spills, no pins needed.
// (r6 post-mortem: demand 120 vs alloc 68 -> ~50 scratch reloads/lane/step.)
__global__ void __launch_bounds__(512)
__attribute__((amdgpu_waves_per_eu(4, 4)))
lstm2_fused(const float* __restrict__ x,      // [512, 2048, 1]
            const float* __restrict__ w_ih1,  // [256, 1]
            const float* __restrict__ w_hh1,  // [256, 64]
            const float* __restrict__ b_ih1,  // [256]
            const float* __restrict__ b_hh1,  // [256]
            const float* __restrict__ w_ih2,  // [64, 64]
            const float* __restrict__ w_hh2,  // [64, 16]
            const float* __restrict__ b_ih2,  // [64]
            const float* __restrict__ b_hh2,  // [64]
            float* __restrict__ out)          // [512, 2048, 16]
{
    const int b   = blockIdx.x;
    const int tid = threadIdx.x;

    __shared__ float x_lds[TSTEPS];
    __shared__ float h1buf[2][H1];
    __shared__ float h2buf[2][H2];
    __shared__ v4f   gbuf4[H1];      // activated L1 gates, [j] = (i,f,t,o)
    __shared__ v4f   g2buf4[H2];     // activated L2 gates, [m] = (i,f,t,o)
    __shared__ float ring[RING][H2]; // h2 output ring, flushed every 32 steps

    // ---- stage x[b,:] (8 KB), zero state buffers ----
    reinterpret_cast<v4f*>(x_lds)[tid] =
        reinterpret_cast<const v4f*>(x + (size_t)b * TSTEPS)[tid];
    if (tid < 2 * H1) ((float*)h1buf)[tid] = 0.0f;
    if (tid < 2 * H2) ((float*)h2buf)[tid] = 0.0f;

    // ---- Layer 1 weights: gate row r1 = g*64+j, k-half s2 ----
    const int j  = tid >> 3;
    const int g  = (tid >> 1) & 3;
    const int s2 = tid & 1;
    const int r1 = g * H1 + j;
    v2f w1[16];
    {
        const v2f* ws = reinterpret_cast<const v2f*>(w_hh1 + r1 * H1 + s2 * 32);
        #pragma unroll
        for (int k = 0; k < 16; ++k) w1[k] = ws[k];
    }
    const float wx1 = w_ih1[r1];
    const float bs1 = b_ih1[r1] + b_hh1[r1];
    const float k21 = (g == 2) ? 2.0f : 1.0f;

    // ---- Layer 2 weights: gate row r2 = g2*16+m, k-slice s8 ----
    const int m  = tid >> 5;
    const int g2 = (tid >> 3) & 3;
    const int s8 = tid & 7;
    const int r2 = g2 * H2 + m;
    v2f w2[4];
    {
        const v2f* ws = reinterpret_cast<const v2f*>(w_ih2 + r2 * H1 + s8 * 8);
        w2[0] = ws[0]; w2[1] = ws[1]; w2[2] = ws[2]; w2[3] = ws[3];
    }
    const v2f wh2 = *reinterpret_cast<const v2f*>(w_hh2 + r2 * H2 + s8 * 2);
    const float bs2 = b_ih2[r2] + b_hh2[r2];
    const float k22 = (g2 == 2) ? 2.0f : 1.0f;

    float c1 = 0.0f;   // replicated across the 8 lanes of channel j
    float c2 = 0.0f;   // replicated across the 32 lanes of channel m
    __syncthreads();

    float* outb = out + (size_t)b * TSTEPS * H2;

    // Layer 2 runs one step behind layer 1; one barrier per step.
    for (int t = 0; t <= TSTEPS; ++t) {
        const int ri = t & 1;                 // h1buf[ri]=h1(t-1), h2buf[ri]=h2(t-2)
        const float* h1o = h1buf[ri];

        // ===== L1 gate row for step t: dot over this lane's k-half =====
        if (t < TSTEPS) {
            const v2f* h2v = reinterpret_cast<const v2f*>(h1o + s2 * 32);
            v2f acc = w1[0] * h2v[0];
            #pragma unroll
            for (int k = 1; k < 16; ++k) acc += w1[k] * h2v[k];
            float s = acc.x + acc.y;
            s = reduce2(s);                                  // full 64-dot
            float av = act(s + wx1 * x_lds[t] + bs1, k21);   // activated gate
            if (s2 == 0) ((float*)gbuf4)[j * 4 + g] = av;    // same-wave slot
        }

        // ===== L2 gate row for step t-1 =====
        if (t >= 1) {
            const v2f* hv = reinterpret_cast<const v2f*>(h1o + s8 * 8);
            v2f acc = w2[0] * hv[0];
            acc += w2[1] * hv[1];
            acc += w2[2] * hv[2];
            acc += w2[3] * hv[3];
            const v2f hp = *reinterpret_cast<const v2f*>(&h2buf[ri][s8 * 2]);
            acc += wh2 * hp;
            float s = reduce8(acc.x + acc.y);                // full 80-dot
            float av = act(s + bs2, k22);
            if (s8 == 0) ((float*)g2buf4)[m * 4 + g2] = av;  // same-wave slot
        }

        // Writers and readers of gbuf4/g2buf4 are in the SAME wave; DS ops from
        // one wave are processed in order. Fence only the compiler:
        __builtin_amdgcn_wave_barrier();

        // ===== cell updates (activated gates gathered via one b128 read) =====
        if (t < TSTEPS) {
            v4f gt = gbuf4[j];                    // (i,f,t,o)
            c1 = gt.y * c1 + gt.x * gt.z;
            float h1n = gt.w * ftanh(c1);
            if ((tid & 7) == 0) h1buf[ri ^ 1][j] = h1n;
        }
        if (t >= 1) {
            v4f gt = g2buf4[m];
            c2 = gt.y * c2 + gt.x * gt.z;
            float h2n = gt.w * ftanh(c2);
            if ((tid & 31) == 0) {
                h2buf[ri ^ 1][m] = h2n;
                ring[(t - 1) & (RING - 1)][m] = h2n;   // LDS only on the step path
            }
        }

        __syncthreads();   // publish h1(t) / h2(t-1) for iteration t+1

        // ---- coalesced output flush every 32 steps (vmcnt drain amortized) ----
        if (t >= RING && (t & (RING - 1)) == 0) {
            // 512 lanes = 32 ring rows x 16 channels, consecutive floats
            float val = ring[tid >> 4][tid & 15];
            outb[(size_t)(t - RING) * H2 + tid] = val;
            __syncthreads();   // ring slot 0 is rewritten next step
        }
    }
}

extern "C" void kernel_launch(void* const* d_in, const int* in_sizes, int n_in,
                              void* d_out, int out_size, void* d_ws, size_t ws_size,
                              hipStream_t stream) {
    const float* x     = (const float*)d_in[0];
    const float* w_ih1 = (const float*)d_in[1];
    const float* w_hh1 = (const float*)d_in[2];
    const float* b_ih1 = (const float*)d_in[3];
    const float* b_hh1 = (const float*)d_in[4];
    const float* w_ih2 = (const float*)d_in[5];
    const float* w_hh2 = (const float*)d_in[6];
    const float* b_ih2 = (const float*)d_in[7];
    const float* b_hh2 = (const float*)d_in[8];
    float* out = (float*)d_out;

    lstm2_fused<<<NBATCH, 512, 0, stream>>>(x, w_ih1, w_hh1, b_ih1, b_hh1,
                                            w_ih2, w_hh2, b_ih2, b_hh2, out);
}